// Round 1
// baseline (65.458 us; speedup 1.0000x reference)
//
#include <hip/hip_runtime.h>
#include <stdint.h>

// JAX threefry PRNG mode: 1 = partitionable (modern default, jax >= 0.4.30),
// 0 = original. Flip to 0 if absmax ~5 comes back (wrong-mode signature).
#ifndef JAX_PARTITIONABLE
#define JAX_PARTITIONABLE 1
#endif

#define MAXL 256  // L = 200 at this problem size

__device__ __forceinline__ uint32_t rotl32(uint32_t x, uint32_t d){
  return (x << d) | (x >> (32u - d));
}

// JAX threefry2x32 block (20 rounds, rotations [13,15,26,6]/[17,29,16,24])
__device__ __forceinline__ void tf2x32(uint32_t k0, uint32_t k1,
                                       uint32_t x0, uint32_t x1,
                                       uint32_t& o0, uint32_t& o1){
  const uint32_t k2 = k0 ^ k1 ^ 0x1BD11BDAu;
  x0 += k0; x1 += k1;
  // group 1 (A), then +ks1, +ks2+1
  x0 += x1; x1 = rotl32(x1,13); x1 ^= x0;
  x0 += x1; x1 = rotl32(x1,15); x1 ^= x0;
  x0 += x1; x1 = rotl32(x1,26); x1 ^= x0;
  x0 += x1; x1 = rotl32(x1, 6); x1 ^= x0;
  x0 += k1; x1 += k2 + 1u;
  // group 2 (B), +ks2, +ks0+2
  x0 += x1; x1 = rotl32(x1,17); x1 ^= x0;
  x0 += x1; x1 = rotl32(x1,29); x1 ^= x0;
  x0 += x1; x1 = rotl32(x1,16); x1 ^= x0;
  x0 += x1; x1 = rotl32(x1,24); x1 ^= x0;
  x0 += k2; x1 += k0 + 2u;
  // group 3 (A), +ks0, +ks1+3
  x0 += x1; x1 = rotl32(x1,13); x1 ^= x0;
  x0 += x1; x1 = rotl32(x1,15); x1 ^= x0;
  x0 += x1; x1 = rotl32(x1,26); x1 ^= x0;
  x0 += x1; x1 = rotl32(x1, 6); x1 ^= x0;
  x0 += k0; x1 += k1 + 3u;
  // group 4 (B), +ks1, +ks2+4
  x0 += x1; x1 = rotl32(x1,17); x1 ^= x0;
  x0 += x1; x1 = rotl32(x1,29); x1 ^= x0;
  x0 += x1; x1 = rotl32(x1,16); x1 ^= x0;
  x0 += x1; x1 = rotl32(x1,24); x1 ^= x0;
  x0 += k1; x1 += k2 + 4u;
  // group 5 (A), +ks2, +ks0+5
  x0 += x1; x1 = rotl32(x1,13); x1 ^= x0;
  x0 += x1; x1 = rotl32(x1,15); x1 ^= x0;
  x0 += x1; x1 = rotl32(x1,26); x1 ^= x0;
  x0 += x1; x1 = rotl32(x1, 6); x1 ^= x0;
  x0 += k2; x1 += k0 + 5u;
  o0 = x0; o1 = x1;
}

#if !JAX_PARTITIONABLE
// original split: out = threefry(key, iota(2n)) with x0=iota[0:n], x1=iota[n:2n];
// word j of the flattened (n,2) result.
__device__ __forceinline__ uint32_t split_word_orig(uint32_t k0, uint32_t k1,
                                                    uint32_t n, uint32_t j){
  uint32_t o0, o1;
  if (j < n){ tf2x32(k0,k1,j,n+j,o0,o1); return o0; }
  tf2x32(k0,k1,j-n,j,o0,o1); return o1;
}
#endif

// i-th subkey of split(key, n)
__device__ __forceinline__ void split_key(uint32_t k0, uint32_t k1, uint32_t n,
                                          uint32_t i, uint32_t& s0, uint32_t& s1){
#if JAX_PARTITIONABLE
  (void)n; tf2x32(k0,k1,0u,i,s0,s1);   // foldlike: key_i = block(key,(0,i))
#else
  s0 = split_word_orig(k0,k1,n,2u*i);
  s1 = split_word_orig(k0,k1,n,2u*i+1u);
#endif
}

// random_bits(key, 32, ()) — scalar
__device__ __forceinline__ uint32_t rbits_scalar(uint32_t k0, uint32_t k1){
  uint32_t o0,o1; tf2x32(k0,k1,0u,0u,o0,o1);
#if JAX_PARTITIONABLE
  return o0 ^ o1;
#else
  return o0;   // odd-size pad path: counts=[0,0], take first word
#endif
}

// jax.random.randint(key, (), 0, span) — exact algorithm from jax._src.random._randint
__device__ __forceinline__ uint32_t jax_randint(uint32_t k0, uint32_t k1, uint32_t span){
  uint32_t a0,a1,b0,b1;
  split_key(k0,k1,2u,0u,a0,a1);
  split_key(k0,k1,2u,1u,b0,b1);
  uint32_t hb = rbits_scalar(a0,a1);
  uint32_t lb = rbits_scalar(b0,b1);
  uint32_t mult = 65536u % span;        // 2^(nbits/2) % span
  mult = (mult * mult) % span;          // 2^32 % span
  return ((hb % span) * mult + (lb % span)) % span;
}

// jax.random.uniform element from raw 32 bits
__device__ __forceinline__ float u01(uint32_t bits){
  return __uint_as_float((bits >> 9) | 0x3F800000u) - 1.0f;
}

__global__ __launch_bounds__(256)
void seqaug_kernel(const float* __restrict__ seq, const int* __restrict__ slen_arr,
                   const float* __restrict__ memb, float* __restrict__ out,
                   int B, int L, int D)
{
  const int b   = blockIdx.x;
  const int tid = threadIdx.x;
  const int Lh  = L >> 1;

  __shared__ uint32_t s_kb[2];          // per-sequence key
  __shared__ uint32_t s_w5[10];         // 5 subkeys (10 words)
  __shared__ int      s_params[4];      // aug_type, crop_len, start_c, start_r
  __shared__ float    s_rand[MAXL];     // reorder sort keys
  __shared__ unsigned char s_mflag[MAXL];
  __shared__ short    s_src[MAXL];      // per-row source: >=0 row, -1 zero, -2 mask_emb
  __shared__ float4   s_memb[64];       // mask_emb as float4 (D/4 <= 64)

  const int slen = slen_arr[b];
  const int f_per_row = D >> 2;

  // ---- phase A: per-sequence key from split(key(42), B); stage mask_emb
  if (tid >= 64 && tid < 64 + f_per_row)
    s_memb[tid - 64] = ((const float4*)memb)[tid - 64];
#if JAX_PARTITIONABLE
  if (tid == 0){
    uint32_t o0,o1; tf2x32(0u, 42u, 0u, (uint32_t)b, o0, o1);
    s_kb[0] = o0; s_kb[1] = o1;
  }
#else
  if (tid < 2) s_kb[tid] = split_word_orig(0u, 42u, (uint32_t)B, (uint32_t)(2*b + tid));
#endif
  __syncthreads();

  // ---- phase B: split(key_b, 5)
#if JAX_PARTITIONABLE
  if (tid < 5){
    uint32_t o0,o1; tf2x32(s_kb[0], s_kb[1], 0u, (uint32_t)tid, o0, o1);
    s_w5[2*tid] = o0; s_w5[2*tid+1] = o1;
  }
#else
  if (tid < 10) s_w5[tid] = split_word_orig(s_kb[0], s_kb[1], 5u, (uint32_t)tid);
#endif
  __syncthreads();

  // ---- phase C: thread 0 scalar randint chain; threads 8..8+L-1 uniforms
  if (tid == 0){
    int aug_type = (int)jax_randint(s_w5[0], s_w5[1], 3u);
    int crop_len = (int)(0.6f * (float)slen);   // f32 mul + trunc, as in JAX
    if (crop_len < 1) crop_len = 1;
    int span_c = slen - crop_len; if (span_c < 0) span_c = 0;
    int start_c = (int)jax_randint(s_w5[2], s_w5[3], (uint32_t)(span_c + 1));
    int re_len = crop_len;                      // same formula, REORDER_RATE == CROP_RATE
    int span_r = slen - re_len; if (span_r < 0) span_r = 0;
    int start_r = (int)jax_randint(s_w5[4], s_w5[5], (uint32_t)(span_r + 1));
    s_params[0] = aug_type; s_params[1] = crop_len;
    s_params[2] = start_c;  s_params[3] = start_r;
  }
  if (tid >= 8 && tid < 8 + L){
    int t = tid - 8;
#if JAX_PARTITIONABLE
    uint32_t o0,o1;
    tf2x32(s_w5[6], s_w5[7], 0u, (uint32_t)t, o0, o1);
    s_rand[t] = u01(o0 ^ o1);
    tf2x32(s_w5[8], s_w5[9], 0u, (uint32_t)t, o0, o1);
    s_mflag[t] = (u01(o0 ^ o1) < 0.3f) ? 1 : 0;
#else
    if (t < Lh){
      uint32_t o0,o1;
      tf2x32(s_w5[6], s_w5[7], (uint32_t)t, (uint32_t)(Lh + t), o0, o1);
      s_rand[t]      = u01(o0);
      s_rand[t + Lh] = u01(o1);
      tf2x32(s_w5[8], s_w5[9], (uint32_t)t, (uint32_t)(Lh + t), o0, o1);
      s_mflag[t]      = (u01(o0) < 0.3f) ? 1 : 0;
      s_mflag[t + Lh] = (u01(o1) < 0.3f) ? 1 : 0;
    }
#endif
  }
  __syncthreads();

  const int aug_type = s_params[0];
  const int crop_len = s_params[1];
  const int start_c  = s_params[2];
  const int start_r  = s_params[3];
  const int re_len   = crop_len;

  // ---- phase D: default per-row source
  if (tid < L){
    int p = tid;
    short src;
    if (aug_type == 0){
      src = (p < crop_len) ? (short)(p + start_c) : (short)-1;
    } else if (aug_type == 1){
      src = (p < slen) ? (short)p : (short)-1;
    } else {
      src = (p >= slen) ? (short)-1 : (s_mflag[p] ? (short)-2 : (short)p);
    }
    s_src[p] = src;
  }
  __syncthreads();

  // ---- phase E: stable-argsort scatter for the reorder window
  if (aug_type == 1 && tid < re_len){
    float kt = s_rand[start_r + tid];
    int rank = 0;
    for (int s = 0; s < re_len; ++s){
      float ks = s_rand[start_r + s];
      rank += (int)((ks < kt) || (ks == kt && s < tid));  // stable tie-break
    }
    s_src[start_r + rank] = (short)(start_r + tid);       // order[rank]=idx; row reads order[p-start_r]
  }
  __syncthreads();

  // ---- phase F: write output rows (float4 vectorized)
  const float4* seq4 = (const float4*)(seq + (size_t)b * L * D);
  float4*       out4 = (float4*)(out + (size_t)b * L * D);
  const float4 zero4 = make_float4(0.f, 0.f, 0.f, 0.f);
  if (f_per_row == 16){
    const int f = tid & 15;
    for (int p = tid >> 4; p < L; p += 16){
      int src = s_src[p];
      float4 v;
      if (src >= 0)       v = seq4[src * 16 + f];
      else if (src == -2) v = s_memb[f];
      else                v = zero4;
      out4[p * 16 + f] = v;
    }
  } else {
    const int total = L * f_per_row;
    for (int idx = tid; idx < total; idx += blockDim.x){
      int p = idx / f_per_row;
      int f = idx - p * f_per_row;
      int src = s_src[p];
      float4 v;
      if (src >= 0)       v = seq4[src * f_per_row + f];
      else if (src == -2) v = s_memb[f];
      else                v = zero4;
      out4[idx] = v;
    }
  }
  // aug_len, stored as float (harness reads the whole buffer as float32)
  if (tid == 0){
    out[(size_t)B * L * D + b] = (float)((aug_type == 0) ? crop_len : slen);
  }
}

extern "C" void kernel_launch(void* const* d_in, const int* in_sizes, int n_in,
                              void* d_out, int out_size, void* d_ws, size_t ws_size,
                              hipStream_t stream) {
  const float* seq  = (const float*)d_in[0];
  const int*   slen = (const int*)  d_in[1];
  const float* memb = (const float*)d_in[2];
  float*       out  = (float*)d_out;
  const int B = in_sizes[1];
  const int D = in_sizes[2];
  const int L = in_sizes[0] / (B * D);
  hipLaunchKernelGGL(seqaug_kernel, dim3(B), dim3(256), 0, stream,
                     seq, slen, memb, out, B, L, D);
}

// Round 2
// 62.626 us; speedup vs baseline: 1.0452x; 1.0452x over previous
//
#include <hip/hip_runtime.h>
#include <stdint.h>

#define MAXL 256  // L = 200 at this problem size

__device__ __forceinline__ uint32_t rotl32(uint32_t x, uint32_t d){
  return (x << d) | (x >> (32u - d));
}

// JAX threefry2x32 block (20 rounds), partitionable mode throughout.
__device__ __forceinline__ void tf2x32(uint32_t k0, uint32_t k1,
                                       uint32_t x0, uint32_t x1,
                                       uint32_t& o0, uint32_t& o1){
  const uint32_t k2 = k0 ^ k1 ^ 0x1BD11BDAu;
  x0 += k0; x1 += k1;
  x0 += x1; x1 = rotl32(x1,13); x1 ^= x0;
  x0 += x1; x1 = rotl32(x1,15); x1 ^= x0;
  x0 += x1; x1 = rotl32(x1,26); x1 ^= x0;
  x0 += x1; x1 = rotl32(x1, 6); x1 ^= x0;
  x0 += k1; x1 += k2 + 1u;
  x0 += x1; x1 = rotl32(x1,17); x1 ^= x0;
  x0 += x1; x1 = rotl32(x1,29); x1 ^= x0;
  x0 += x1; x1 = rotl32(x1,16); x1 ^= x0;
  x0 += x1; x1 = rotl32(x1,24); x1 ^= x0;
  x0 += k2; x1 += k0 + 2u;
  x0 += x1; x1 = rotl32(x1,13); x1 ^= x0;
  x0 += x1; x1 = rotl32(x1,15); x1 ^= x0;
  x0 += x1; x1 = rotl32(x1,26); x1 ^= x0;
  x0 += x1; x1 = rotl32(x1, 6); x1 ^= x0;
  x0 += k0; x1 += k1 + 3u;
  x0 += x1; x1 = rotl32(x1,17); x1 ^= x0;
  x0 += x1; x1 = rotl32(x1,29); x1 ^= x0;
  x0 += x1; x1 = rotl32(x1,16); x1 ^= x0;
  x0 += x1; x1 = rotl32(x1,24); x1 ^= x0;
  x0 += k1; x1 += k2 + 4u;
  x0 += x1; x1 = rotl32(x1,13); x1 ^= x0;
  x0 += x1; x1 = rotl32(x1,15); x1 ^= x0;
  x0 += x1; x1 = rotl32(x1,26); x1 ^= x0;
  x0 += x1; x1 = rotl32(x1, 6); x1 ^= x0;
  x0 += k2; x1 += k0 + 5u;
  o0 = x0; o1 = x1;
}

// jax.random.uniform element from raw 32 bits
__device__ __forceinline__ float u01(uint32_t bits){
  return __uint_as_float((bits >> 9) | 0x3F800000u) - 1.0f;
}

// randint combine from two 32-bit draws (jax._src.random._randint)
__device__ __forceinline__ uint32_t randint_comb(uint32_t hb, uint32_t lb, uint32_t span){
  uint32_t mult = 65536u % span;   // 2^16 % span
  mult = (mult * mult) % span;     // 2^32 % span
  return ((hb % span) * mult + (lb % span)) % span;
}

__global__ __launch_bounds__(256)
void seqaug_kernel(const float* __restrict__ seq, const int* __restrict__ slen_arr,
                   const float* __restrict__ memb, float* __restrict__ out,
                   int B, int L, int D)
{
  const int b   = blockIdx.x;
  const int tid = threadIdx.x;

  __shared__ int    s_params[4];        // aug_type, crop_len, start_c, start_r
  __shared__ float  s_rand[MAXL];       // reorder sort keys
  __shared__ int    s_src[MAXL];        // per-row source: >=0 row, -1 zero, -2 mask_emb
  __shared__ float4 s_memb[64];         // mask_emb as float4

  const int slen = slen_arr[b];
  const int f_per_row = D >> 2;

  // ---- phase 1 (no barrier yet): everyone derives the per-seq key redundantly
  uint32_t kb0, kb1;
  tf2x32(0u, 42u, 0u, (uint32_t)b, kb0, kb1);   // split(key(42),B)[b], partitionable

  int mflag = 0;  // mask flag for row `tid`, kept in register
  if (tid < L){
    uint32_t a0,a1,c0,c1,r0,r1,m0,m1;
    tf2x32(kb0, kb1, 0u, 3u, a0, a1);            // k_reo_perm
    tf2x32(kb0, kb1, 0u, 4u, c0, c1);            // k_mask   (independent → ILP)
    tf2x32(a0, a1, 0u, (uint32_t)tid, r0, r1);
    tf2x32(c0, c1, 0u, (uint32_t)tid, m0, m1);
    s_rand[tid] = u01(r0 ^ r1);
    mflag = (u01(m0 ^ m1) < 0.3f) ? 1 : 0;
  }
  if (tid >= 224 && tid < 224 + f_per_row)
    s_memb[tid - 224] = ((const float4*)memb)[tid - 224];

  // wave 0: lane-parallel randint chain. Lane p (p<6): param=p>>1, word j=p&1.
  if (tid < 64){
    uint32_t param = (uint32_t)(tid >> 1);
    uint32_t j     = (uint32_t)(tid & 1);
    uint32_t w0,w1,s0,s1,r0,r1;
    tf2x32(kb0, kb1, 0u, param, w0, w1);   // split(key_b,5)[param]
    tf2x32(w0, w1, 0u, j, s0, s1);         // split(k_param,2)[j]
    tf2x32(s0, s1, 0u, 0u, r0, r1);        // random_bits scalar
    uint32_t bits = r0 ^ r1;
    uint32_t hb_a = __shfl(bits, 0), lb_a = __shfl(bits, 1);
    uint32_t hb_c = __shfl(bits, 2), lb_c = __shfl(bits, 3);
    uint32_t hb_r = __shfl(bits, 4), lb_r = __shfl(bits, 5);
    if (tid == 0){
      int aug_type = (int)randint_comb(hb_a, lb_a, 3u);
      int crop_len = (int)(0.6f * (float)slen);      // f32 mul + trunc, as in JAX
      if (crop_len < 1) crop_len = 1;
      int span = slen - crop_len; if (span < 0) span = 0;   // re_len == crop_len
      int start_c = (int)randint_comb(hb_c, lb_c, (uint32_t)(span + 1));
      int start_r = (int)randint_comb(hb_r, lb_r, (uint32_t)(span + 1));
      s_params[0] = aug_type; s_params[1] = crop_len;
      s_params[2] = start_c;  s_params[3] = start_r;
    }
  }
  __syncthreads();   // barrier #1

  const int aug_type = s_params[0];
  const int crop_len = s_params[1];
  const int start_c  = s_params[2];
  const int start_r  = s_params[3];
  const int re_len   = crop_len;

  // ---- phase 2: per-row source. Window rows (aug==1) are written ONLY by the
  // rank-scatter below → disjoint writers, single phase, no extra barrier.
  if (tid < L){
    int p = tid;
    if (aug_type == 0){
      s_src[p] = (p < crop_len) ? (p + start_c) : -1;
    } else if (aug_type == 1){
      bool inwin = (p >= start_r) && (p < start_r + re_len);
      if (!inwin) s_src[p] = (p < slen) ? p : -1;
    } else {
      s_src[p] = (p >= slen) ? -1 : (mflag ? -2 : p);
    }
  }
  if (aug_type == 1 && tid < re_len){
    float kt = s_rand[start_r + tid];
    int rank = 0;
    for (int s = 0; s < re_len; ++s){
      float ks = s_rand[start_r + s];               // same addr all lanes → broadcast
      rank += (int)((ks < kt) || (ks == kt && s < tid));  // stable tie-break
    }
    s_src[start_r + rank] = start_r + tid;          // order[rank]=idx
  }
  __syncthreads();   // barrier #2

  // ---- phase 3: write output rows (float4 vectorized, 1KB/wave stores)
  const float4* seq4 = (const float4*)(seq + (size_t)b * L * D);
  float4*       out4 = (float4*)(out + (size_t)b * L * D);
  const float4 zero4 = make_float4(0.f, 0.f, 0.f, 0.f);
  if (f_per_row == 16){
    const int f = tid & 15;
    for (int p = tid >> 4; p < L; p += 16){
      int src = s_src[p];
      float4 v;
      if (src >= 0)       v = seq4[src * 16 + f];
      else if (src == -2) v = s_memb[f];
      else                v = zero4;
      out4[p * 16 + f] = v;
    }
  } else {
    const int total = L * f_per_row;
    for (int idx = tid; idx < total; idx += blockDim.x){
      int p = idx / f_per_row;
      int f = idx - p * f_per_row;
      int src = s_src[p];
      float4 v;
      if (src >= 0)       v = seq4[src * f_per_row + f];
      else if (src == -2) v = s_memb[f];
      else                v = zero4;
      out4[idx] = v;
    }
  }
  // aug_len, stored as float (harness reads the whole buffer as float32)
  if (tid == 0){
    out[(size_t)B * L * D + b] = (float)((aug_type == 0) ? crop_len : slen);
  }
}

extern "C" void kernel_launch(void* const* d_in, const int* in_sizes, int n_in,
                              void* d_out, int out_size, void* d_ws, size_t ws_size,
                              hipStream_t stream) {
  const float* seq  = (const float*)d_in[0];
  const int*   slen = (const int*)  d_in[1];
  const float* memb = (const float*)d_in[2];
  float*       out  = (float*)d_out;
  const int B = in_sizes[1];
  const int D = in_sizes[2];
  const int L = in_sizes[0] / (B * D);
  hipLaunchKernelGGL(seqaug_kernel, dim3(B), dim3(256), 0, stream,
                     seq, slen, memb, out, B, L, D);
}

// Round 3
// 61.730 us; speedup vs baseline: 1.0604x; 1.0145x over previous
//
#include <hip/hip_runtime.h>
#include <stdint.h>

#define MAXL 256  // L = 200 at this problem size

typedef float f4 __attribute__((ext_vector_type(4)));

__device__ __forceinline__ uint32_t rotl32(uint32_t x, uint32_t d){
  return (x << d) | (x >> (32u - d));
}

// JAX threefry2x32 block (20 rounds), partitionable mode.
__device__ __forceinline__ void tf2x32(uint32_t k0, uint32_t k1,
                                       uint32_t x0, uint32_t x1,
                                       uint32_t& o0, uint32_t& o1){
  const uint32_t k2 = k0 ^ k1 ^ 0x1BD11BDAu;
  x0 += k0; x1 += k1;
  x0 += x1; x1 = rotl32(x1,13); x1 ^= x0;
  x0 += x1; x1 = rotl32(x1,15); x1 ^= x0;
  x0 += x1; x1 = rotl32(x1,26); x1 ^= x0;
  x0 += x1; x1 = rotl32(x1, 6); x1 ^= x0;
  x0 += k1; x1 += k2 + 1u;
  x0 += x1; x1 = rotl32(x1,17); x1 ^= x0;
  x0 += x1; x1 = rotl32(x1,29); x1 ^= x0;
  x0 += x1; x1 = rotl32(x1,16); x1 ^= x0;
  x0 += x1; x1 = rotl32(x1,24); x1 ^= x0;
  x0 += k2; x1 += k0 + 2u;
  x0 += x1; x1 = rotl32(x1,13); x1 ^= x0;
  x0 += x1; x1 = rotl32(x1,15); x1 ^= x0;
  x0 += x1; x1 = rotl32(x1,26); x1 ^= x0;
  x0 += x1; x1 = rotl32(x1, 6); x1 ^= x0;
  x0 += k0; x1 += k1 + 3u;
  x0 += x1; x1 = rotl32(x1,17); x1 ^= x0;
  x0 += x1; x1 = rotl32(x1,29); x1 ^= x0;
  x0 += x1; x1 = rotl32(x1,16); x1 ^= x0;
  x0 += x1; x1 = rotl32(x1,24); x1 ^= x0;
  x0 += k1; x1 += k2 + 4u;
  x0 += x1; x1 = rotl32(x1,13); x1 ^= x0;
  x0 += x1; x1 = rotl32(x1,15); x1 ^= x0;
  x0 += x1; x1 = rotl32(x1,26); x1 ^= x0;
  x0 += x1; x1 = rotl32(x1, 6); x1 ^= x0;
  x0 += k2; x1 += k0 + 5u;
  o0 = x0; o1 = x1;
}

__device__ __forceinline__ float u01(uint32_t bits){
  return __uint_as_float((bits >> 9) | 0x3F800000u) - 1.0f;
}

__device__ __forceinline__ uint32_t randint_comb(uint32_t hb, uint32_t lb, uint32_t span){
  uint32_t mult = 65536u % span;   // 2^16 % span
  mult = (mult * mult) % span;     // 2^32 % span
  return ((hb % span) * mult + (lb % span)) % span;
}

// ---------------- Kernel A: per-sequence PRNG + source-row table ----------------
// Writes d_src[b*L+p] = absolute source row (b*L + src), or -1 (zero) / -2 (mask).
// Also writes aug_len into the output tail.
__global__ __launch_bounds__(256)
void params_kernel(const int* __restrict__ slen_arr, int* __restrict__ d_src,
                   float* __restrict__ out_tail, int B, int L)
{
  const int b   = blockIdx.x;
  const int tid = threadIdx.x;

  __shared__ int    s_params[4];        // aug_type, crop_len, start_c, start_r
  __shared__ float  s_rand[MAXL];       // reorder sort keys
  __shared__ int    s_src[MAXL];        // per-row source: >=0 row, -1 zero, -2 mask

  const int slen = slen_arr[b];

  // per-seq key (redundant per thread, 1 block)
  uint32_t kb0, kb1;
  tf2x32(0u, 42u, 0u, (uint32_t)b, kb0, kb1);   // split(key(42),B)[b]

  int mflag = 0;
  if (tid < L){
    uint32_t a0,a1,c0,c1,r0,r1,m0,m1;
    tf2x32(kb0, kb1, 0u, 3u, a0, a1);            // k_reo_perm
    tf2x32(kb0, kb1, 0u, 4u, c0, c1);            // k_mask (independent -> ILP)
    tf2x32(a0, a1, 0u, (uint32_t)tid, r0, r1);
    tf2x32(c0, c1, 0u, (uint32_t)tid, m0, m1);
    s_rand[tid] = u01(r0 ^ r1);
    mflag = (u01(m0 ^ m1) < 0.3f) ? 1 : 0;
  }

  // wave 0: lane-parallel randint chain. Lane p (p<6): param=p>>1, word j=p&1.
  if (tid < 64){
    uint32_t param = (uint32_t)(tid >> 1);
    uint32_t j     = (uint32_t)(tid & 1);
    uint32_t w0,w1,s0,s1,r0,r1;
    tf2x32(kb0, kb1, 0u, param, w0, w1);   // split(key_b,5)[param]
    tf2x32(w0, w1, 0u, j, s0, s1);         // split(k_param,2)[j]
    tf2x32(s0, s1, 0u, 0u, r0, r1);        // random_bits scalar
    uint32_t bits = r0 ^ r1;
    uint32_t hb_a = __shfl(bits, 0), lb_a = __shfl(bits, 1);
    uint32_t hb_c = __shfl(bits, 2), lb_c = __shfl(bits, 3);
    uint32_t hb_r = __shfl(bits, 4), lb_r = __shfl(bits, 5);
    if (tid == 0){
      int aug_type = (int)randint_comb(hb_a, lb_a, 3u);
      int crop_len = (int)(0.6f * (float)slen);      // f32 mul + trunc, as in JAX
      if (crop_len < 1) crop_len = 1;
      int span = slen - crop_len; if (span < 0) span = 0;   // re_len == crop_len
      int start_c = (int)randint_comb(hb_c, lb_c, (uint32_t)(span + 1));
      int start_r = (int)randint_comb(hb_r, lb_r, (uint32_t)(span + 1));
      s_params[0] = aug_type; s_params[1] = crop_len;
      s_params[2] = start_c;  s_params[3] = start_r;
      out_tail[b] = (float)((aug_type == 0) ? crop_len : slen);
    }
  }
  __syncthreads();   // barrier #1

  const int aug_type = s_params[0];
  const int crop_len = s_params[1];
  const int start_c  = s_params[2];
  const int start_r  = s_params[3];
  const int re_len   = crop_len;

  // per-row source. Window rows (aug==1) written ONLY by the rank-scatter
  // below -> disjoint writers, single phase.
  if (tid < L){
    int p = tid;
    if (aug_type == 0){
      s_src[p] = (p < crop_len) ? (p + start_c) : -1;
    } else if (aug_type == 1){
      bool inwin = (p >= start_r) && (p < start_r + re_len);
      if (!inwin) s_src[p] = (p < slen) ? p : -1;
    } else {
      s_src[p] = (p >= slen) ? -1 : (mflag ? -2 : p);
    }
  }
  if (aug_type == 1 && tid < re_len){
    float kt = s_rand[start_r + tid];
    int rank = 0;
    for (int s = 0; s < re_len; ++s){
      float ks = s_rand[start_r + s];               // broadcast read
      rank += (int)((ks < kt) || (ks == kt && s < tid));  // stable tie-break
    }
    s_src[start_r + rank] = start_r + tid;          // order[rank]=idx
  }
  __syncthreads();   // barrier #2

  if (tid < L){
    int s = s_src[tid];
    d_src[b * L + tid] = (s >= 0) ? (b * L + s) : s;   // absolute source row
  }
}

// ---------------- Kernel B: pure gather/scatter streamer ----------------
// D == 64 specialization: 16 float4 per row, 16 rows per 256-thread block.
__global__ __launch_bounds__(256)
void scatter_kernel_d64(const f4* __restrict__ seq4, const f4* __restrict__ memb4,
                        const int* __restrict__ d_src, f4* __restrict__ out4,
                        int n_rows)
{
  const int t   = blockIdx.x * 256 + threadIdx.x;
  const int row = t >> 4;
  const int f   = t & 15;
  if (row >= n_rows) return;
  const int src = d_src[row];
  f4 v = {0.f, 0.f, 0.f, 0.f};
  if (src >= 0)       v = seq4[src * 16 + f];
  else if (src == -2) v = memb4[f];
  __builtin_nontemporal_store(v, &out4[(size_t)row * 16 + f]);
}

// generic D fallback
__global__ __launch_bounds__(256)
void scatter_kernel_gen(const f4* __restrict__ seq4, const f4* __restrict__ memb4,
                        const int* __restrict__ d_src, f4* __restrict__ out4,
                        int n_rows, int f_per_row)
{
  const int t = blockIdx.x * 256 + threadIdx.x;
  const int row = t / f_per_row;
  const int f   = t - row * f_per_row;
  if (row >= n_rows) return;
  const int src = d_src[row];
  f4 v = {0.f, 0.f, 0.f, 0.f};
  if (src >= 0)       v = seq4[src * f_per_row + f];
  else if (src == -2) v = memb4[f];
  __builtin_nontemporal_store(v, &out4[(size_t)row * f_per_row + f]);
}

extern "C" void kernel_launch(void* const* d_in, const int* in_sizes, int n_in,
                              void* d_out, int out_size, void* d_ws, size_t ws_size,
                              hipStream_t stream) {
  const float* seq  = (const float*)d_in[0];
  const int*   slen = (const int*)  d_in[1];
  const float* memb = (const float*)d_in[2];
  float*       out  = (float*)d_out;
  const int B = in_sizes[1];
  const int D = in_sizes[2];
  const int L = in_sizes[0] / (B * D);

  int* d_src = (int*)d_ws;                 // B*L ints (3.3 MB) in workspace

  hipLaunchKernelGGL(params_kernel, dim3(B), dim3(256), 0, stream,
                     slen, d_src, out + (size_t)B * L * D, B, L);

  const int n_rows = B * L;
  const int fpr = D >> 2;
  const long total4 = (long)n_rows * fpr;
  const int grid = (int)((total4 + 255) / 256);
  if (fpr == 16){
    hipLaunchKernelGGL(scatter_kernel_d64, dim3(grid), dim3(256), 0, stream,
                       (const f4*)seq, (const f4*)memb, d_src, (f4*)out, n_rows);
  } else {
    hipLaunchKernelGGL(scatter_kernel_gen, dim3(grid), dim3(256), 0, stream,
                       (const f4*)seq, (const f4*)memb, d_src, (f4*)out, n_rows, fpr);
  }
}

// Round 4
// 55.691 us; speedup vs baseline: 1.1754x; 1.1084x over previous
//
#include <hip/hip_runtime.h>
#include <stdint.h>

#define MAXL 256  // L = 200 at this problem size

typedef float f4 __attribute__((ext_vector_type(4)));

__device__ __forceinline__ uint32_t rotl32(uint32_t x, uint32_t d){
  return (x << d) | (x >> (32u - d));
}

// JAX threefry2x32 block (20 rounds), partitionable mode.
__device__ __forceinline__ void tf2x32(uint32_t k0, uint32_t k1,
                                       uint32_t x0, uint32_t x1,
                                       uint32_t& o0, uint32_t& o1){
  const uint32_t k2 = k0 ^ k1 ^ 0x1BD11BDAu;
  x0 += k0; x1 += k1;
  x0 += x1; x1 = rotl32(x1,13); x1 ^= x0;
  x0 += x1; x1 = rotl32(x1,15); x1 ^= x0;
  x0 += x1; x1 = rotl32(x1,26); x1 ^= x0;
  x0 += x1; x1 = rotl32(x1, 6); x1 ^= x0;
  x0 += k1; x1 += k2 + 1u;
  x0 += x1; x1 = rotl32(x1,17); x1 ^= x0;
  x0 += x1; x1 = rotl32(x1,29); x1 ^= x0;
  x0 += x1; x1 = rotl32(x1,16); x1 ^= x0;
  x0 += x1; x1 = rotl32(x1,24); x1 ^= x0;
  x0 += k2; x1 += k0 + 2u;
  x0 += x1; x1 = rotl32(x1,13); x1 ^= x0;
  x0 += x1; x1 = rotl32(x1,15); x1 ^= x0;
  x0 += x1; x1 = rotl32(x1,26); x1 ^= x0;
  x0 += x1; x1 = rotl32(x1, 6); x1 ^= x0;
  x0 += k0; x1 += k1 + 3u;
  x0 += x1; x1 = rotl32(x1,17); x1 ^= x0;
  x0 += x1; x1 = rotl32(x1,29); x1 ^= x0;
  x0 += x1; x1 = rotl32(x1,16); x1 ^= x0;
  x0 += x1; x1 = rotl32(x1,24); x1 ^= x0;
  x0 += k1; x1 += k2 + 4u;
  x0 += x1; x1 = rotl32(x1,13); x1 ^= x0;
  x0 += x1; x1 = rotl32(x1,15); x1 ^= x0;
  x0 += x1; x1 = rotl32(x1,26); x1 ^= x0;
  x0 += x1; x1 = rotl32(x1, 6); x1 ^= x0;
  x0 += k2; x1 += k0 + 5u;
  o0 = x0; o1 = x1;
}

__device__ __forceinline__ float u01(uint32_t bits){
  return __uint_as_float((bits >> 9) | 0x3F800000u) - 1.0f;
}

__device__ __forceinline__ uint32_t randint_comb(uint32_t hb, uint32_t lb, uint32_t span){
  uint32_t mult = 65536u % span;   // 2^16 % span
  mult = (mult * mult) % span;     // 2^32 % span
  return ((hb % span) * mult + (lb % span)) % span;
}

// ---------------- Kernel A: per-sequence params + source-row table ----------------
// d_src[b*L+p] = absolute source row (b*L + src), or -1 (zero) / -2 (mask_emb).
// Per-row PRNG is computed ONLY for the branch the sequence actually takes.
__global__ __launch_bounds__(256)
void params_kernel(const int* __restrict__ slen_arr, int* __restrict__ d_src,
                   float* __restrict__ out_tail, int B, int L)
{
  const int b    = blockIdx.x;
  const int tid  = threadIdx.x;
  const int base = b * L;

  __shared__ int   s_params[4];        // aug_type, crop_len, start_c, start_r
  __shared__ float s_rand[MAXL];       // reorder sort keys (window-relative)

  const int slen = slen_arr[b];

  // per-seq key (cheap, redundant per thread)
  uint32_t kb0, kb1;
  tf2x32(0u, 42u, 0u, (uint32_t)b, kb0, kb1);   // split(key(42),B)[b]

  // wave 0: lane-parallel randint chain. Lane p (p<6): param=p>>1, word j=p&1.
  if (tid < 64){
    uint32_t param = (uint32_t)(tid >> 1);
    uint32_t j     = (uint32_t)(tid & 1);
    uint32_t w0,w1,s0,s1,r0,r1;
    tf2x32(kb0, kb1, 0u, param, w0, w1);   // split(key_b,5)[param]
    tf2x32(w0, w1, 0u, j, s0, s1);         // split(k_param,2)[j]
    tf2x32(s0, s1, 0u, 0u, r0, r1);        // random_bits scalar
    uint32_t bits = r0 ^ r1;
    uint32_t hb_a = __shfl(bits, 0), lb_a = __shfl(bits, 1);
    uint32_t hb_c = __shfl(bits, 2), lb_c = __shfl(bits, 3);
    uint32_t hb_r = __shfl(bits, 4), lb_r = __shfl(bits, 5);
    if (tid == 0){
      int aug_type = (int)randint_comb(hb_a, lb_a, 3u);
      int crop_len = (int)(0.6f * (float)slen);      // f32 mul + trunc, as in JAX
      if (crop_len < 1) crop_len = 1;
      int span = slen - crop_len; if (span < 0) span = 0;   // re_len == crop_len
      int start_c = (int)randint_comb(hb_c, lb_c, (uint32_t)(span + 1));
      int start_r = (int)randint_comb(hb_r, lb_r, (uint32_t)(span + 1));
      s_params[0] = aug_type; s_params[1] = crop_len;
      s_params[2] = start_c;  s_params[3] = start_r;
      out_tail[b] = (float)((aug_type == 0) ? crop_len : slen);
    }
  }
  __syncthreads();

  const int aug_type = s_params[0];
  const int crop_len = s_params[1];   // == re_len
  const int start_c  = s_params[2];
  const int start_r  = s_params[3];

  if (aug_type == 0){
    // crop: pure arithmetic, no per-row PRNG
    if (tid < L)
      d_src[base + tid] = (tid < crop_len) ? (base + tid + start_c) : -1;
  } else if (aug_type == 2){
    // mask: per-row uniform only
    if (tid < L){
      uint32_t c0,c1,m0,m1;
      tf2x32(kb0, kb1, 0u, 4u, c0, c1);                 // k_mask
      tf2x32(c0, c1, 0u, (uint32_t)tid, m0, m1);
      int mflag = (u01(m0 ^ m1) < 0.3f) ? 1 : 0;
      d_src[base + tid] = (tid >= slen) ? -1 : (mflag ? -2 : (base + tid));
    }
  } else {
    // reorder: keys only for the window, then stable-rank scatter (direct to global)
    const int re_len = crop_len;
    if (tid < re_len){
      uint32_t a0,a1,r0,r1;
      tf2x32(kb0, kb1, 0u, 3u, a0, a1);                 // k_reo_perm
      tf2x32(a0, a1, 0u, (uint32_t)(start_r + tid), r0, r1);
      s_rand[tid] = u01(r0 ^ r1);
    }
    // non-window rows: direct
    if (tid < L){
      bool inwin = (tid >= start_r) && (tid < start_r + re_len);
      if (!inwin) d_src[base + tid] = (tid < slen) ? (base + tid) : -1;
    }
    __syncthreads();   // keys visible (block-uniform branch -> legal)
    if (tid < re_len){
      float kt = s_rand[tid];
      int rank = 0;
      for (int s = 0; s < re_len; ++s){
        float ks = s_rand[s];                            // broadcast read
        rank += (int)((ks < kt) || (ks == kt && s < tid));  // stable tie-break
      }
      d_src[base + start_r + rank] = base + start_r + tid;  // order[rank]=idx
    }
  }
}

// ---------------- Kernel B: pure gather/scatter streamer ----------------
// D == 64: 16 float4 per row, 16 rows per 256-thread block. NT loads+stores
// on the bulk streams (zero reuse) so caches stay out of the way.
__global__ __launch_bounds__(256)
void scatter_kernel_d64(const f4* __restrict__ seq4, const f4* __restrict__ memb4,
                        const int* __restrict__ d_src, f4* __restrict__ out4,
                        int n_rows)
{
  const int t   = blockIdx.x * 256 + threadIdx.x;
  const int row = t >> 4;
  const int f   = t & 15;
  if (row >= n_rows) return;
  const int src = d_src[row];
  f4 v = {0.f, 0.f, 0.f, 0.f};
  if (src >= 0)       v = __builtin_nontemporal_load(&seq4[(size_t)src * 16 + f]);
  else if (src == -2) v = memb4[f];   // 256B total, stays L2-hot
  __builtin_nontemporal_store(v, &out4[(size_t)row * 16 + f]);
}

// generic D fallback
__global__ __launch_bounds__(256)
void scatter_kernel_gen(const f4* __restrict__ seq4, const f4* __restrict__ memb4,
                        const int* __restrict__ d_src, f4* __restrict__ out4,
                        int n_rows, int f_per_row)
{
  const int t = blockIdx.x * 256 + threadIdx.x;
  const int row = t / f_per_row;
  const int f   = t - row * f_per_row;
  if (row >= n_rows) return;
  const int src = d_src[row];
  f4 v = {0.f, 0.f, 0.f, 0.f};
  if (src >= 0)       v = __builtin_nontemporal_load(&seq4[(size_t)src * f_per_row + f]);
  else if (src == -2) v = memb4[f];
  __builtin_nontemporal_store(v, &out4[(size_t)row * f_per_row + f]);
}

extern "C" void kernel_launch(void* const* d_in, const int* in_sizes, int n_in,
                              void* d_out, int out_size, void* d_ws, size_t ws_size,
                              hipStream_t stream) {
  const float* seq  = (const float*)d_in[0];
  const int*   slen = (const int*)  d_in[1];
  const float* memb = (const float*)d_in[2];
  float*       out  = (float*)d_out;
  const int B = in_sizes[1];
  const int D = in_sizes[2];
  const int L = in_sizes[0] / (B * D);

  int* d_src = (int*)d_ws;                 // B*L ints (3.3 MB) in workspace

  hipLaunchKernelGGL(params_kernel, dim3(B), dim3(256), 0, stream,
                     slen, d_src, out + (size_t)B * L * D, B, L);

  const int n_rows = B * L;
  const int fpr = D >> 2;
  const long total4 = (long)n_rows * fpr;
  const int grid = (int)((total4 + 255) / 256);
  if (fpr == 16){
    hipLaunchKernelGGL(scatter_kernel_d64, dim3(grid), dim3(256), 0, stream,
                       (const f4*)seq, (const f4*)memb, d_src, (f4*)out, n_rows);
  } else {
    hipLaunchKernelGGL(scatter_kernel_gen, dim3(grid), dim3(256), 0, stream,
                       (const f4*)seq, (const f4*)memb, d_src, (f4*)out, n_rows, fpr);
  }
}